// Round 2
// baseline (114.219 us; speedup 1.0000x reference)
//
#include <hip/hip_runtime.h>

// Problem: N=512, D=512, all fp32.
// pre_i[i,h] = sum_d he[i,d] * W0[h, d]        (NT gemm, h<512)
// pre_j[j,h] = sum_d he[j,d] * W0[h, 512+d]
// p[i,j] = sum_h relu(pre_i[i,h] + pre_j[j,h] + b0[h]) * w1[h]  (W1_b dropped: softmax-invariant)
// out = softmax_rows(p) @ h_e
//
// ws layout (floats): Cpart[2][512][1024] | Ppart[8][512][512] | Aw[512][512]
// Cfull[i][c]: c<512 -> pre_i[i][c]; c>=512 -> pre_j[i][c-512]

#define LDS_STRIDE 68  // 64 + 4 pad: bank = (4k + m') pattern -> <=2-way conflicts (free)

// ---------------------------------------------------------------------------
// Kernel A: K-split NT GEMM  Cpart[s][i][c] = sum_{d in slice s} he[i,d] * W0[c&511, ofs(c)+d]
// grid (16 c-tiles, 8 i-tiles, 2 d-slices), block 256, 64x64 tile, BK=32, 4x4 micro
__global__ __launch_bounds__(256) void k_pre(const float* __restrict__ he,
                                             const float* __restrict__ w0,
                                             float* __restrict__ Cpart) {
    const int tid = threadIdx.x;
    const int tx = tid & 15, ty = tid >> 4;
    const int c0 = blockIdx.x * 64;
    const int i0 = blockIdx.y * 64;
    const int kbase0 = blockIdx.z * 256;
    // weight-block decode: rows of W0 are the hidden index, cols are d (+512 for the j-half)
    const int hrow0 = c0 & 511;
    const int dofs  = (c0 >= 512) ? 512 : 0;

    __shared__ float As[32 * LDS_STRIDE];  // [d][i] (transposed)
    __shared__ float Bs[32 * LDS_STRIDE];  // [d][c] (transposed)

    float acc[4][4] = {};

    for (int kt = 0; kt < 8; ++kt) {
        const int kb = kbase0 + kt * 32;   // d-slice base, in [0,512)
        // stage A tile (64 i x 32 d), coalesced float4 reads, transposed scatter writes
        #pragma unroll
        for (int r = 0; r < 2; ++r) {
            int f = tid + r * 256;          // 0..511
            int row = f >> 3;               // 0..63
            int kc = (f & 7) * 4;           // 0..28
            const float4 a = *(const float4*)&he[(i0 + row) * 512 + kb + kc];
            As[(kc + 0) * LDS_STRIDE + row] = a.x;
            As[(kc + 1) * LDS_STRIDE + row] = a.y;
            As[(kc + 2) * LDS_STRIDE + row] = a.z;
            As[(kc + 3) * LDS_STRIDE + row] = a.w;
        }
        // stage W tile (64 c-rows x 32 d-cols), coalesced along weight row, transposed
        #pragma unroll
        for (int r = 0; r < 2; ++r) {
            int f = tid + r * 256;
            int row = f >> 3;               // 0..63 (c within tile)
            int kc = (f & 7) * 4;           // 0..28 (d within slice)
            const float4 b = *(const float4*)&w0[(hrow0 + row) * 1024 + dofs + kb + kc];
            Bs[(kc + 0) * LDS_STRIDE + row] = b.x;
            Bs[(kc + 1) * LDS_STRIDE + row] = b.y;
            Bs[(kc + 2) * LDS_STRIDE + row] = b.z;
            Bs[(kc + 3) * LDS_STRIDE + row] = b.w;
        }
        __syncthreads();
        #pragma unroll
        for (int k = 0; k < 32; ++k) {
            const float4 a = *(const float4*)&As[k * LDS_STRIDE + 4 * ty];
            const float4 b = *(const float4*)&Bs[k * LDS_STRIDE + 4 * tx];
            const float av[4] = {a.x, a.y, a.z, a.w};
            const float bv[4] = {b.x, b.y, b.z, b.w};
            #pragma unroll
            for (int ii = 0; ii < 4; ++ii)
                #pragma unroll
                for (int jj = 0; jj < 4; ++jj)
                    acc[ii][jj] = fmaf(av[ii], bv[jj], acc[ii][jj]);
        }
        __syncthreads();
    }
    float* outp = Cpart + (size_t)blockIdx.z * 512 * 1024;
    #pragma unroll
    for (int ii = 0; ii < 4; ++ii) {
        float4 v = make_float4(acc[ii][0], acc[ii][1], acc[ii][2], acc[ii][3]);
        *(float4*)&outp[(i0 + 4 * ty + ii) * 1024 + c0 + 4 * tx] = v;
    }
}

// ---------------------------------------------------------------------------
// Kernel B: Ppart[hs][i][j] = sum_{h in slice hs} relu(preI[i,h] + cj[j,h]) * w1[h]
// Partial-sum of Cpart (+bias) folded into staging.
// grid (8 j-tiles, 8 i-tiles, 8 h-slices of 64), block 256, 64x64 tile, BK=32, 4x4 micro
__global__ __launch_bounds__(256) void k_score(const float* __restrict__ Cpart,
                                               const float* __restrict__ b0,
                                               const float* __restrict__ w1,
                                               float* __restrict__ Ppart) {
    const int tid = threadIdx.x;
    const int tx = tid & 15, ty = tid >> 4;
    const int j0 = blockIdx.x * 64;
    const int i0 = blockIdx.y * 64;
    const int hs = blockIdx.z;
    const float* C0 = Cpart;
    const float* C1 = Cpart + 512 * 1024;

    __shared__ float As[32 * LDS_STRIDE];  // [h][i]
    __shared__ float Bs[32 * LDS_STRIDE];  // [h][j]
    __shared__ float Ws[32];

    float acc[4][4] = {};

    for (int kt = 0; kt < 2; ++kt) {
        const int hb = hs * 64 + kt * 32;
        // preI tile: sum the two d-slice partials of Cfull[:, h]
        #pragma unroll
        for (int r = 0; r < 2; ++r) {
            int f = tid + r * 256;
            int row = f >> 3;
            int hc = (f & 7) * 4;
            int g = (i0 + row) * 1024 + hb + hc;
            float4 a = *(const float4*)&C0[g];
            float4 a1 = *(const float4*)&C1[g];
            As[(hc + 0) * LDS_STRIDE + row] = a.x + a1.x;
            As[(hc + 1) * LDS_STRIDE + row] = a.y + a1.y;
            As[(hc + 2) * LDS_STRIDE + row] = a.z + a1.z;
            As[(hc + 3) * LDS_STRIDE + row] = a.w + a1.w;
        }
        // cj tile: Cfull[:, 512+h] partial-sum + bias b0[h]
        #pragma unroll
        for (int r = 0; r < 2; ++r) {
            int f = tid + r * 256;
            int row = f >> 3;
            int hc = (f & 7) * 4;
            int g = (j0 + row) * 1024 + 512 + hb + hc;
            float4 a = *(const float4*)&C0[g];
            float4 a1 = *(const float4*)&C1[g];
            float4 bb = *(const float4*)&b0[hb + hc];
            Bs[(hc + 0) * LDS_STRIDE + row] = a.x + a1.x + bb.x;
            Bs[(hc + 1) * LDS_STRIDE + row] = a.y + a1.y + bb.y;
            Bs[(hc + 2) * LDS_STRIDE + row] = a.z + a1.z + bb.z;
            Bs[(hc + 3) * LDS_STRIDE + row] = a.w + a1.w + bb.w;
        }
        if (tid < 32) Ws[tid] = w1[hb + tid];
        __syncthreads();
        #pragma unroll
        for (int k = 0; k < 32; ++k) {
            const float4 a = *(const float4*)&As[k * LDS_STRIDE + 4 * ty];
            const float4 b = *(const float4*)&Bs[k * LDS_STRIDE + 4 * tx];
            const float w = Ws[k];
            const float av[4] = {a.x, a.y, a.z, a.w};
            const float bv[4] = {b.x, b.y, b.z, b.w};
            #pragma unroll
            for (int ii = 0; ii < 4; ++ii)
                #pragma unroll
                for (int jj = 0; jj < 4; ++jj)
                    acc[ii][jj] = fmaf(fmaxf(av[ii] + bv[jj], 0.0f), w, acc[ii][jj]);
        }
        __syncthreads();
    }
    float* outp = Ppart + (size_t)hs * 512 * 512;
    #pragma unroll
    for (int ii = 0; ii < 4; ++ii) {
        float4 v = make_float4(acc[ii][0], acc[ii][1], acc[ii][2], acc[ii][3]);
        *(float4*)&outp[(i0 + 4 * ty + ii) * 512 + j0 + 4 * tx] = v;
    }
}

// ---------------------------------------------------------------------------
// Kernel C1: reduce 8 P-partials, row softmax -> Aw[i][j]. grid(512), block 256.
__global__ __launch_bounds__(256) void k_softmax(const float* __restrict__ Ppart,
                                                 float* __restrict__ Aw) {
    const int i = blockIdx.x;
    const int tid = threadIdx.x;
    float p0 = 0.f, p1 = 0.f;
    #pragma unroll
    for (int s = 0; s < 8; ++s) {
        p0 += Ppart[s * 262144 + i * 512 + tid];
        p1 += Ppart[s * 262144 + i * 512 + tid + 256];
    }
    __shared__ float red[256];
    red[tid] = fmaxf(p0, p1);
    __syncthreads();
    for (int s = 128; s > 0; s >>= 1) {
        if (tid < s) red[tid] = fmaxf(red[tid], red[tid + s]);
        __syncthreads();
    }
    const float m = red[0];
    __syncthreads();
    const float e0 = __expf(p0 - m);
    const float e1 = __expf(p1 - m);
    red[tid] = e0 + e1;
    __syncthreads();
    for (int s = 128; s > 0; s >>= 1) {
        if (tid < s) red[tid] += red[tid + s];
        __syncthreads();
    }
    const float inv = 1.0f / red[0];
    Aw[i * 512 + tid] = e0 * inv;
    Aw[i * 512 + tid + 256] = e1 * inv;
}

// ---------------------------------------------------------------------------
// Kernel C2: out = Aw @ h_e. grid (16 d-tiles, 16 i-tiles), block 256,
// 32x32 tile, BK=32, 2x2 micro.
__global__ __launch_bounds__(256) void k_out(const float* __restrict__ Aw,
                                             const float* __restrict__ he,
                                             float* __restrict__ outp) {
    const int tid = threadIdx.x;
    const int tx = tid & 15, ty = tid >> 4;
    const int d0 = blockIdx.x * 32;
    const int i0 = blockIdx.y * 32;
    __shared__ float As[32 * 34];  // [k][i], stride 34 (8B-aligned float2 rows)
    __shared__ float Bs[32 * 36];  // [k][d], stride 36 (16B-aligned float4 rows)
    float acc[2][2] = {};
    for (int kt = 0; kt < 16; ++kt) {
        const int kb = kt * 32;
        {   // stage A (32 i x 32 k) transposed
            int row = tid >> 3;            // 0..31
            int kc = (tid & 7) * 4;
            float4 a = *(const float4*)&Aw[(i0 + row) * 512 + kb + kc];
            As[(kc + 0) * 34 + row] = a.x;
            As[(kc + 1) * 34 + row] = a.y;
            As[(kc + 2) * 34 + row] = a.z;
            As[(kc + 3) * 34 + row] = a.w;
        }
        {   // stage B (32 k x 32 d) natural
            int row = tid >> 3;
            int dc = (tid & 7) * 4;
            *(float4*)&Bs[row * 36 + dc] = *(const float4*)&he[(kb + row) * 512 + d0 + dc];
        }
        __syncthreads();
        #pragma unroll
        for (int k = 0; k < 32; ++k) {
            const float2 a = *(const float2*)&As[k * 34 + 2 * ty];
            const float2 b = *(const float2*)&Bs[k * 36 + 2 * tx];
            acc[0][0] = fmaf(a.x, b.x, acc[0][0]);
            acc[0][1] = fmaf(a.x, b.y, acc[0][1]);
            acc[1][0] = fmaf(a.y, b.x, acc[1][0]);
            acc[1][1] = fmaf(a.y, b.y, acc[1][1]);
        }
        __syncthreads();
    }
    #pragma unroll
    for (int ii = 0; ii < 2; ++ii) {
        float2 v = make_float2(acc[ii][0], acc[ii][1]);
        *(float2*)&outp[(i0 + 2 * ty + ii) * 512 + d0 + 2 * tx] = v;
    }
}

extern "C" void kernel_launch(void* const* d_in, const int* in_sizes, int n_in,
                              void* d_out, int out_size, void* d_ws, size_t ws_size,
                              hipStream_t stream) {
    const float* he = (const float*)d_in[0];   // (512, 512)
    const float* w0 = (const float*)d_in[1];   // (512, 1024)
    const float* b0 = (const float*)d_in[2];   // (512,)
    const float* w1 = (const float*)d_in[3];   // (1, 512)
    // d_in[4] = W1_b: softmax-invariant, intentionally unused.
    float* outp = (float*)d_out;               // (512, 512)

    float* Cpart = (float*)d_ws;               // 2 * 512 * 1024
    float* Ppart = Cpart + 2 * 512 * 1024;     // 8 * 512 * 512
    float* Aw    = Ppart + 8 * 512 * 512;      // 512 * 512

    k_pre    <<<dim3(16, 8, 2), 256, 0, stream>>>(he, w0, Cpart);
    k_score  <<<dim3(8, 8, 8),  256, 0, stream>>>(Cpart, b0, w1, Ppart);
    k_softmax<<<dim3(512),      256, 0, stream>>>(Ppart, Aw);
    k_out    <<<dim3(16, 16),   256, 0, stream>>>(Aw, he, outp);
}